// Round 11
// baseline (132.238 us; speedup 1.0000x reference)
//
#include <hip/hip_runtime.h>

// Problem constants: B=2, N=2048, C=1024, H=16, hd=64
// x:(2,2048,1024) f32; Wqkv:(1024,3072); Wproj:(1024,1024); bproj:(1024); q_scale,k_scale:(64)
// out:(2,2048,1024) f32

typedef _Float16 half_t;
typedef __attribute__((ext_vector_type(2))) __fp16 fp16x2;
typedef __attribute__((ext_vector_type(4))) _Float16 half4v;
typedef __attribute__((ext_vector_type(8))) _Float16 half8;
typedef __attribute__((ext_vector_type(4))) float f32x4;
typedef __attribute__((ext_vector_type(4))) unsigned uint4v;

#define DI __device__ __forceinline__

DI void gl_lds16(const void* g, void* l) {
    __builtin_amdgcn_global_load_lds((const __attribute__((address_space(1))) void*)g,
                                     (__attribute__((address_space(3))) void*)l, 16, 0, 0);
}

DI float exp2_fast(float x) {
    float r;
    asm("v_exp_f32 %0, %1" : "=v"(r) : "v"(x));
    return r;
}

// v_permlane32_swap_b32: a.rows[2,3] <-> b.rows[0,1] (rows = 16-lane groups)
DI void pl32_swap(unsigned& a, unsigned& b) {
    asm("v_permlane32_swap_b32 %0, %1" : "+v"(a), "+v"(b));
}
// v_permlane16_swap_b32: a.rows[1,3] <-> b.rows[0,2]
DI void pl16_swap(unsigned& a, unsigned& b) {
    asm("v_permlane16_swap_b32 %0, %1" : "+v"(a), "+v"(b));
}

DI unsigned pk_u32(float lo, float hi) {
    fp16x2 t = __builtin_amdgcn_cvt_pkrtz(lo, hi);
    return *(unsigned*)&t;
}

// ---------------- merged prep kernel ----------------
// blocks [0,4096): x f32->fp16 ; [4096,7168): Wqkv transpose->fp16 ; [7168,8192): Wproj
__global__ void prep_all(const float* __restrict__ x, const float* __restrict__ Wqkv,
                         const float* __restrict__ Wproj, half_t* __restrict__ xh,
                         half_t* __restrict__ wqt, half_t* __restrict__ wpt) {
    __shared__ float t[32][33];
    int bid = blockIdx.x;
    if (bid < 4096) {
        int i = (bid * 256 + threadIdx.x) * 4;
        float4 v = *(const float4*)(x + i);
        half4v o;
        o[0] = (half_t)v.x; o[1] = (half_t)v.y; o[2] = (half_t)v.z; o[3] = (half_t)v.w;
        *(half4v*)(xh + i) = o;
    } else if (bid < 4096 + 3072) {
        int i = bid - 4096;
        int c0 = (i % 96) * 32, r0 = (i / 96) * 32;
        int tx = threadIdx.x & 31, ty = threadIdx.x >> 5;
#pragma unroll
        for (int k = 0; k < 4; k++)
            t[ty + 8 * k][tx] = Wqkv[(size_t)(r0 + ty + 8 * k) * 3072 + c0 + tx];
        __syncthreads();
#pragma unroll
        for (int k = 0; k < 4; k++)
            wqt[(size_t)(c0 + ty + 8 * k) * 1024 + r0 + tx] = (half_t)t[tx][ty + 8 * k];
    } else {
        int i = bid - 4096 - 3072;
        int c0 = (i % 32) * 32, r0 = (i / 32) * 32;
        int tx = threadIdx.x & 31, ty = threadIdx.x >> 5;
#pragma unroll
        for (int k = 0; k < 4; k++)
            t[ty + 8 * k][tx] = Wproj[(size_t)(r0 + ty + 8 * k) * 1024 + c0 + tx];
        __syncthreads();
#pragma unroll
        for (int k = 0; k < 4; k++)
            wpt[(size_t)(c0 + ty + 8 * k) * 1024 + r0 + tx] = (half_t)t[tx][ty + 8 * k];
    }
}

// ---------------- QKV GEMM: fp16, BK=64, dbuf LDS, fused RMSNorm epilogue ----------------
__global__ __launch_bounds__(256) void gemm_qkv(
    const half_t* __restrict__ A, const half_t* __restrict__ Bt,
    const float* __restrict__ qs, const float* __restrict__ ks,
    half_t* __restrict__ qh, half_t* __restrict__ kh, half_t* __restrict__ vth) {
    const int K = 1024;
    __shared__ __align__(16) half_t Al[2][128 * 64];
    __shared__ __align__(16) half_t Bl[2][128 * 64];
    int tid = threadIdx.x;
    int w = tid >> 6, l = tid & 63;
    int wr = w >> 1, wc = w & 1;
    int g = l >> 4, r = l & 15;
    int m0 = blockIdx.x * 128, n0 = blockIdx.y * 128;
    f32x4 acc[4][4] = {};

#define STAGE_QKV(kt, buf)                                                        \
    {                                                                             \
        _Pragma("unroll")                                                         \
        for (int p = 0; p < 4; p++) {                                             \
            int ci = p * 256 + tid;                                               \
            int row = ci >> 3, c = ci & 7, lc = c ^ (row & 7);                    \
            gl_lds16(A + (size_t)(m0 + row) * K + (kt) * 64 + lc * 8,             \
                     &Al[buf][0] + ci * 8);                                       \
            gl_lds16(Bt + (size_t)(n0 + row) * K + (kt) * 64 + lc * 8,            \
                     &Bl[buf][0] + ci * 8);                                       \
        }                                                                         \
    }

    STAGE_QKV(0, 0);
    __syncthreads();
    int cur = 0;
    for (int kt = 0; kt < 16; kt++) {
        if (kt < 15) STAGE_QKV(kt + 1, cur ^ 1);
#pragma unroll
        for (int ks2 = 0; ks2 < 2; ks2++) {
            half8 af[4], bf[4];
#pragma unroll
            for (int i = 0; i < 4; i++) {
                int row = wr * 64 + i * 16 + r;
                af[i] = *(const half8*)(&Al[cur][0] + row * 64 + (((4 * ks2 + g) ^ (row & 7)) << 3));
                int rowb = wc * 64 + i * 16 + r;
                bf[i] = *(const half8*)(&Bl[cur][0] + rowb * 64 + (((4 * ks2 + g) ^ (rowb & 7)) << 3));
            }
#pragma unroll
            for (int i = 0; i < 4; i++)
#pragma unroll
                for (int j = 0; j < 4; j++)
                    acc[i][j] = __builtin_amdgcn_mfma_f32_16x16x32_f16(af[i], bf[j], acc[i][j], 0, 0, 0);
        }
        __syncthreads();
        cur ^= 1;
    }

    int tsec = n0 >> 10;  // 0=q, 1=k, 2=v (uniform per block)
    if (tsec == 2) {
#pragma unroll
        for (int i = 0; i < 4; i++)
#pragma unroll
            for (int j = 0; j < 4; j++) {
                int gcol = n0 + wc * 64 + j * 16 + r;
                int h = (gcol >> 6) & 15;
                int f = gcol & 63;
                int growb = m0 + wr * 64 + i * 16 + g * 4;
                int b = growb >> 11;
                int n = growb & 2047;
                half4v pv;
#pragma unroll
                for (int rr = 0; rr < 4; rr++) pv[rr] = (half_t)acc[i][j][rr];
                *(half4v*)(vth + ((size_t)(b * 16 + h) * 64 + f) * 2048 + n) = pv;
            }
    } else {
        const float* sc = (tsec == 0) ? qs : ks;
        half_t* dst = (tsec == 0) ? qh : kh;
        float extra = (tsec == 0) ? (0.125f * 1.44269504f) : 1.0f;  // fold hd^-0.5*log2e into q
        float scv[4];
#pragma unroll
        for (int j = 0; j < 4; j++) scv[j] = sc[j * 16 + r];
#pragma unroll
        for (int i = 0; i < 4; i++)
#pragma unroll
            for (int rr = 0; rr < 4; rr++) {
                float ss = 0.f;
#pragma unroll
                for (int j = 0; j < 4; j++) ss += acc[i][j][rr] * acc[i][j][rr];
#pragma unroll
                for (int d = 1; d < 16; d <<= 1) ss += __shfl_xor(ss, d, 64);
                float inv = extra / (sqrtf(ss) * 0.125f + 1e-8f);  // rms = ||row||/8
                int grow = m0 + wr * 64 + i * 16 + g * 4 + rr;
                int b = grow >> 11;
                int n = grow & 2047;
#pragma unroll
                for (int j = 0; j < 4; j++) {
                    int gcol = n0 + wc * 64 + j * 16 + r;
                    int h = (gcol >> 6) & 15;
                    int f = gcol & 63;
                    dst[((size_t)(b * 16 + h) * 2048 + n) * 64 + f] =
                        (half_t)(acc[i][j][rr] * inv * scv[j]);
                }
            }
    }
}

// ---------------- flash attention: 32 q-rows/wave, permlane PV, no P-LDS -----------
// grid (16 q-tiles, 32 bh), 256 thr = 4 waves, each wave 32 q-rows (2 groups of 16).
// KEY: every wave reads the FULL K/V tile from LDS (they are the shared A-operands).
// Doubling q-rows/wave amortizes each K-frag/V-frag read over 2 MFMAs -> LDS read
// traffic halves (2.1 GB -> 1.05 GB), the binding resource per the R10 counters.
// S^T = mfma(K_frag, Q_frag[qg]): lane(g,r) holds S^T[kv=16tt+4g+reg][q], log2 units.
// PV B-frag built in-register via cvt_pkrtz + permlane32/16 swaps (R10-verified).
// Defer-max THR=11, predicate-only common path; independent m/lsum per q-group.
// (PROVEN numerics; no-max variant failed 4.7e-2 — keep max tracking.)
__global__ __launch_bounds__(256, 2) void attn(
    const half_t* __restrict__ qh, const half_t* __restrict__ kh,
    const half_t* __restrict__ vth, half_t* __restrict__ aoh) {
    int bh = blockIdx.y;
    int q0 = blockIdx.x * 128;
    const half_t* Qp = qh + (size_t)bh * 2048 * 64;
    const half_t* Kp = kh + (size_t)bh * 2048 * 64;
    const half_t* Vp = vth + (size_t)bh * 64 * 2048;  // (feat, n)
    __shared__ __align__(16) half_t Kl[2][64 * 64];
    __shared__ __align__(16) half_t Vl[2][64 * 64];   // [feat][kv]
    int tid = threadIdx.x, w = tid >> 6, l = tid & 63, g = l >> 4, r = l & 15;

    // staging: 512 chunks of 16B per 64x64 fp16 buffer, 2 chunks/thread
    const half_t* kstp[2];
    const half_t* vstp[2];
    int ldsoff[2];
#pragma unroll
    for (int p = 0; p < 2; p++) {
        int ci = p * 256 + tid;
        int row = ci >> 3, c = ci & 7, lc = c ^ (row & 7);
        kstp[p] = Kp + (size_t)row * 64 + lc * 8;
        vstp[p] = Vp + (size_t)row * 2048 + lc * 8;
        ldsoff[p] = ci * 8;
    }

    // hoisted LDS element-offsets (loop-invariant)
    int koff[8], voff[8];
#pragma unroll
    for (int ks = 0; ks < 2; ks++)
#pragma unroll
        for (int tt = 0; tt < 4; tt++) {
            int row = tt * 16 + r;
            koff[ks * 4 + tt] = row * 64 + (((4 * ks + g) ^ (row & 7)) << 3);
        }
#pragma unroll
    for (int ks2 = 0; ks2 < 2; ks2++)
#pragma unroll
        for (int cf = 0; cf < 4; cf++) {
            int row = cf * 16 + r;
            voff[ks2 * 4 + cf] = row * 64 + (((4 * ks2 + g) ^ (row & 7)) << 3);
        }

    // Q fragments: 2 groups, Q[q = q0 + w*32 + qg*16 + r][hd = 32ks + 8g + e]
    half8 qf[2][2];
#pragma unroll
    for (int qg = 0; qg < 2; qg++)
#pragma unroll
        for (int ks = 0; ks < 2; ks++)
            qf[qg][ks] = *(const half8*)(Qp + (size_t)(q0 + w * 32 + qg * 16 + r) * 64 + ks * 32 + g * 8);

    f32x4 o[2][4] = {};          // per group: O^T[d = 16cf + 4g + reg][q]
    float m0v = -1e30f, m1v = -1e30f, ls0 = 0.f, ls1 = 0.f;

    // prologue: stage tile 0
#pragma unroll
    for (int p = 0; p < 2; p++) {
        gl_lds16(kstp[p], &Kl[0][0] + ldsoff[p]);
        gl_lds16(vstp[p], &Vl[0][0] + ldsoff[p]);
    }
    __syncthreads();

#define ATTN_TILE(BUF, T)                                                          \
    {                                                                              \
        if ((T) < 31) {                                                            \
            _Pragma("unroll")                                                      \
            for (int p = 0; p < 2; p++) {                                          \
                gl_lds16(kstp[p] + ((T) + 1) * 4096, &Kl[(BUF) ^ 1][0] + ldsoff[p]); \
                gl_lds16(vstp[p] + ((T) + 1) * 64, &Vl[(BUF) ^ 1][0] + ldsoff[p]); \
            }                                                                      \
        }                                                                          \
        const half_t* Kc = &Kl[BUF][0];                                            \
        const half_t* Vc = &Vl[BUF][0];                                            \
        f32x4 s[2][4] = {};                                                        \
        _Pragma("unroll")                                                          \
        for (int ks = 0; ks < 2; ks++)                                             \
            _Pragma("unroll")                                                      \
            for (int tt = 0; tt < 4; tt++) {                                       \
                half8 kf = *(const half8*)(Kc + koff[ks * 4 + tt]);                \
                s[0][tt] = __builtin_amdgcn_mfma_f32_16x16x32_f16(kf, qf[0][ks], s[0][tt], 0, 0, 0); \
                s[1][tt] = __builtin_amdgcn_mfma_f32_16x16x32_f16(kf, qf[1][ks], s[1][tt], 0, 0, 0); \
            }                                                                      \
        float thr0 = m0v + 11.0f, thr1 = m1v + 11.0f;                              \
        bool ok = true;                                                            \
        _Pragma("unroll")                                                          \
        for (int tt = 0; tt < 4; tt++)                                             \
            _Pragma("unroll")                                                      \
            for (int e = 0; e < 4; e++)                                            \
                ok = ok && (s[0][tt][e] <= thr0) && (s[1][tt][e] <= thr1);         \
        if (!__all(ok)) {                                                          \
            float mx0 = -1e30f, mx1 = -1e30f;                                      \
            _Pragma("unroll")                                                      \
            for (int tt = 0; tt < 4; tt++)                                         \
                _Pragma("unroll")                                                  \
                for (int e = 0; e < 4; e++) {                                      \
                    mx0 = fmaxf(mx0, s[0][tt][e]);                                 \
                    mx1 = fmaxf(mx1, s[1][tt][e]);                                 \
                }                                                                  \
            mx0 = fmaxf(mx0, __shfl_xor(mx0, 16, 64));                             \
            mx0 = fmaxf(mx0, __shfl_xor(mx0, 32, 64));                             \
            mx1 = fmaxf(mx1, __shfl_xor(mx1, 16, 64));                             \
            mx1 = fmaxf(mx1, __shfl_xor(mx1, 32, 64));                             \
            float mn0 = fmaxf(m0v, mx0), mn1 = fmaxf(m1v, mx1);                    \
            float f0 = exp2_fast(m0v - mn0), f1 = exp2_fast(m1v - mn1);            \
            ls0 *= f0; ls1 *= f1;                                                  \
            _Pragma("unroll")                                                      \
            for (int cf = 0; cf < 4; cf++)                                         \
                _Pragma("unroll")                                                  \
                for (int e = 0; e < 4; e++) {                                      \
                    o[0][cf][e] *= f0;                                             \
                    o[1][cf][e] *= f1;                                             \
                }                                                                  \
            m0v = mn0; m1v = mn1;                                                  \
        }                                                                          \
        _Pragma("unroll")                                                          \
        for (int tt = 0; tt < 4; tt++)                                             \
            _Pragma("unroll")                                                      \
            for (int e = 0; e < 4; e++) {                                          \
                float p0 = exp2_fast(s[0][tt][e] - m0v);                           \
                float p1 = exp2_fast(s[1][tt][e] - m1v);                           \
                s[0][tt][e] = p0; ls0 += p0;                                       \
                s[1][tt][e] = p1; ls1 += p1;                                       \
            }                                                                      \
        _Pragma("unroll")                                                          \
        for (int ks2 = 0; ks2 < 2; ks2++) {                                        \
            half8 pf[2];                                                           \
            _Pragma("unroll")                                                      \
            for (int qg = 0; qg < 2; qg++) {                                       \
                unsigned b0 = pk_u32(s[qg][2 * ks2][0], s[qg][2 * ks2][1]);        \
                unsigned b1 = pk_u32(s[qg][2 * ks2][2], s[qg][2 * ks2][3]);        \
                unsigned b2 = pk_u32(s[qg][2 * ks2 + 1][0], s[qg][2 * ks2 + 1][1]); \
                unsigned b3 = pk_u32(s[qg][2 * ks2 + 1][2], s[qg][2 * ks2 + 1][3]); \
                pl32_swap(b0, b2); pl16_swap(b0, b2);                              \
                pl32_swap(b1, b3); pl16_swap(b1, b3);                              \
                uint4v pw; pw[0] = b0; pw[1] = b1; pw[2] = b2; pw[3] = b3;         \
                pf[qg] = *(half8*)&pw;                                             \
            }                                                                      \
            _Pragma("unroll")                                                      \
            for (int cf = 0; cf < 4; cf++) {                                       \
                half8 vf = *(const half8*)(Vc + voff[ks2 * 4 + cf]);               \
                o[0][cf] = __builtin_amdgcn_mfma_f32_16x16x32_f16(vf, pf[0], o[0][cf], 0, 0, 0); \
                o[1][cf] = __builtin_amdgcn_mfma_f32_16x16x32_f16(vf, pf[1], o[1][cf], 0, 0, 0); \
            }                                                                      \
        }                                                                          \
        __syncthreads();                                                           \
    }

    for (int t = 0; t < 32; t += 2) {
        ATTN_TILE(0, t);
        ATTN_TILE(1, t + 1);
    }

    // cross-lane (g-group) sum: lanes r, r+16, r+32, r+48 hold disjoint kv-slots
    ls0 += __shfl_xor(ls0, 16, 64);
    ls0 += __shfl_xor(ls0, 32, 64);
    ls1 += __shfl_xor(ls1, 16, 64);
    ls1 += __shfl_xor(ls1, 32, 64);

    int b = bh >> 4, h = bh & 15;
#pragma unroll
    for (int qg = 0; qg < 2; qg++) {
        int n = q0 + w * 32 + qg * 16 + r;
        float inv = 1.0f / (qg ? ls1 : ls0);
#pragma unroll
        for (int cf = 0; cf < 4; cf++) {
            half4v ov;
#pragma unroll
            for (int reg = 0; reg < 4; reg++) ov[reg] = (half_t)(o[qg][cf][reg] * inv);
            *(half4v*)(aoh + ((size_t)b * 2048 + n) * 1024 + h * 64 + cf * 16 + g * 4) = ov;
        }
    }
}

// ---------------- proj GEMM: fp16, BK=64, + bias, f32 out ----------------
__global__ __launch_bounds__(256) void gemm_proj(
    const half_t* __restrict__ A, const half_t* __restrict__ Bt,
    const float* __restrict__ bias, float* __restrict__ out) {
    const int K = 1024;
    __shared__ __align__(16) half_t Al[128 * 64];
    __shared__ __align__(16) half_t Bl[128 * 64];
    int tid = threadIdx.x, w = tid >> 6, l = tid & 63;
    int wr = w >> 1, wc = w & 1, g = l >> 4, r = l & 15;
    int m0 = blockIdx.x * 128, n0 = blockIdx.y * 128;
    f32x4 acc[4][4] = {};

    for (int k0 = 0; k0 < K; k0 += 64) {
#pragma unroll
        for (int p = 0; p < 4; p++) {
            int ci = (p * 4 + w) * 64 + l;
            int row = ci >> 3, c = ci & 7;
            int lc = c ^ (row & 7);
            gl_lds16(A + (size_t)(m0 + row) * K + k0 + lc * 8, Al + (p * 4 + w) * 512);
            gl_lds16(Bt + (size_t)(n0 + row) * K + k0 + lc * 8, Bl + (p * 4 + w) * 512);
        }
        __syncthreads();
#pragma unroll
        for (int ks = 0; ks < 2; ks++) {
            half8 af[4], bf[4];
#pragma unroll
            for (int i = 0; i < 4; i++) {
                int row = wr * 64 + i * 16 + r;
                af[i] = *(const half8*)(Al + row * 64 + (((4 * ks + g) ^ (row & 7)) << 3));
                int rowb = wc * 64 + i * 16 + r;
                bf[i] = *(const half8*)(Bl + rowb * 64 + (((4 * ks + g) ^ (rowb & 7)) << 3));
            }
#pragma unroll
            for (int i = 0; i < 4; i++)
#pragma unroll
                for (int j = 0; j < 4; j++)
                    acc[i][j] = __builtin_amdgcn_mfma_f32_16x16x32_f16(af[i], bf[j], acc[i][j], 0, 0, 0);
        }
        __syncthreads();
    }

#pragma unroll
    for (int i = 0; i < 4; i++)
#pragma unroll
        for (int j = 0; j < 4; j++) {
            int gcol = n0 + wc * 64 + j * 16 + r;
            float bv = bias[gcol];
#pragma unroll
            for (int rr = 0; rr < 4; rr++) {
                int grow = m0 + wr * 64 + i * 16 + g * 4 + rr;
                out[(size_t)grow * 1024 + gcol] = acc[i][j][rr] + bv;
            }
        }
}

// ---------------- launch ----------------
extern "C" void kernel_launch(void* const* d_in, const int* in_sizes, int n_in,
                              void* d_out, int out_size, void* d_ws, size_t ws_size,
                              hipStream_t stream) {
    const float* x = (const float*)d_in[0];
    const float* Wqkv = (const float*)d_in[1];
    const float* Wproj = (const float*)d_in[2];
    const float* bproj = (const float*)d_in[3];
    const float* qscale = (const float*)d_in[4];
    const float* kscale = (const float*)d_in[5];
    float* out = (float*)d_out;

    char* ws = (char*)d_ws;
    half_t* xh  = (half_t*)(ws + 0);         //  8.0 MB (4096 x 1024 fp16)
    half_t* wqt = (half_t*)(ws + 8388608);   //  6.0 MB (3072 x 1024 fp16, transposed)
    half_t* wpt = (half_t*)(ws + 14680064);  //  2.0 MB (1024 x 1024 fp16, transposed)
    half_t* qh  = (half_t*)(ws + 16777216);  //  8.0 MB (b,h,n,f)
    half_t* kh  = (half_t*)(ws + 25165824);  //  8.0 MB (b,h,n,f)
    half_t* vth = (half_t*)(ws + 33554432);  //  8.0 MB (b,h,f,n)
    half_t* aoh = (half_t*)(ws + 41943040);  //  8.0 MB (b,n,c)

    prep_all<<<8192, 256, 0, stream>>>(x, Wqkv, Wproj, xh, wqt, wpt);
    gemm_qkv<<<dim3(32, 24), 256, 0, stream>>>(xh, wqt, qscale, kscale, qh, kh, vth);
    attn<<<dim3(16, 32), 256, 0, stream>>>(qh, kh, vth, aoh);
    gemm_proj<<<dim3(32, 8), 256, 0, stream>>>(aoh, wpt, bproj, out);
}